// Round 19
// baseline (2152.923 us; speedup 1.0000x reference)
//
#include <hip/hip_runtime.h>
#include <hip/hip_bf16.h>
#include <stdint.h>

typedef __attribute__((ext_vector_type(8))) short bf16x8;
typedef __attribute__((ext_vector_type(4))) float f32x4;
typedef __attribute__((ext_vector_type(4))) float floatv4;
typedef __attribute__((ext_vector_type(8))) unsigned short ushortx8;

// fp32 -> bf16 round-to-nearest-even (finite inputs)
__device__ __forceinline__ unsigned short f2bf(float f) {
  union { float f; uint32_t u; } c; c.f = f;
  uint32_t u = c.u;
  uint32_t r = (u + 0x7FFFu + ((u >> 16) & 1u)) >> 16;
  return (unsigned short)r;
}

// single kernel converts BOTH tensors (dst is contiguous: [x_bf16 | w_bf16])
__global__ void cvt_dual(const float* __restrict__ x, const float* __restrict__ w,
                         unsigned short* __restrict__ dst, size_t nx8, size_t nt8) {
  size_t i = (size_t)blockIdx.x * blockDim.x + threadIdx.x;
  size_t stride = (size_t)gridDim.x * blockDim.x;
  for (size_t j = i; j < nt8; j += stride) {
    const float* src = (j < nx8) ? x : w - nx8 * 8;   // src[j*8] indexes the right tensor
    floatv4 v0 = ((const floatv4*)src)[j * 2];
    floatv4 v1 = ((const floatv4*)src)[j * 2 + 1];
    ushortx8 o;
    o[0] = f2bf(v0[0]); o[1] = f2bf(v0[1]); o[2] = f2bf(v0[2]); o[3] = f2bf(v0[3]);
    o[4] = f2bf(v1[0]); o[5] = f2bf(v1[1]); o[6] = f2bf(v1[2]); o[7] = f2bf(v1[3]);
    ((ushortx8*)dst)[j] = o;
  }
}

// ------ 256x256 BK=32 bf16 GEMM (C = A*B^T + bias), 64 KiB LDS -> 2 blocks/CU ------
// 512 threads = 8 waves (2M x 4N), per-wave output 128x64, 16x16x32 MFMA (K=32/tile).
// LDS 64 KiB: A[2buf][256][32] + B[2buf][256][32] bf16 (16 KiB per tile per matrix).
// 2 blocks/CU (launch_bounds 512,4): cross-block pipe overlap — one block's MFMA
// phase fills the other's read/barrier stalls (m114 mechanism, impossible at 1 blk).
//
// Swizzle (64B row = 4x16B slots): read slot' = l16 ^ ((l15>>1)&3) — per-lane const
// since (R>>1)&3 == (l15>>1)&3 for all fragment rows (mi*16, q*64, wm*128 are %4==0
// in units of 2 rows). Bank check: lanes {i, i+8} share a bank -> 2-way = free.
// Staging pre-applies the same involution on the global source k-offset.
//
// r16 2-phase ledger, re-parametrized (each tile = 1 STG = 2 global_load_lds):
//  P0(t): read a0(4)+b1(2) <-BUF; stage A(t+1)->NBUF; Q(a0,b0)+Q(a0,b1);
//         LGKM0; BAR
//  P1(t): read a1(4) <-BUF; stage B(t+2)->BUF; Q(a1,b1)+Q(a1,b0);
//         VMCNT(2); LGKM0; BAR; pre-read b0(t+1)<-NBUF
// vmcnt ledger: entering P0(t): 2 outstanding {B(t+1)}; +2 (A(t+1)) = 4;
//  +2 (B(t+2)) = 6; VMCNT(2) completes the 4 oldest = B(t+1)+A(t+1) -> next tile
//  fully staged (all waves) before BAR -> pre-read b0(t+1)/P0(t+1) reads safe.
//  Prologue: A(0),B(0),B(1) = 6 loads; VMCNT(2) completes A(0),B(0).
//  Tails: t==Kt-2 -> VMCNT(0); t==Kt-1 -> no stage/VMCNT/pre-read.
// WAR: LGKM0 before EVERY closing BAR forces ds_read retirement pre-barrier
//  (r14 hazard closed). A(t+1)@P0(t): NBUF-A reads (a0/a1 of t-1) retired by
//  P0/P1(t-1) LGKM0 >=1 BAR. B(t+2)@P1(t): BUF-B reads b1(t) retired P0(t)-end,
//  b0(t) (pre-read P1(t-1)-end, consumed P0(t)) retired P0(t)-end >=1 BAR.
// Requires Kt even (launcher guards; else fallback kernel).

#define BAR()     do { asm volatile("" ::: "memory"); __builtin_amdgcn_s_barrier(); asm volatile("" ::: "memory"); } while (0)
#define VMCNT(n)  asm volatile("s_waitcnt vmcnt(" #n ")" ::: "memory")
#define LGKM0()   asm volatile("s_waitcnt lgkmcnt(0)" ::: "memory")

// stage one full 256x32 tile (16 KiB) via 2x global_load_lds(16B)/thread.
// lbase = 0 (A) / 16384 (B); bufe = LITERAL 0 / 8192; t_ feeds only the global k.
#define STG(sp, lbase, bufe, t_) do {                                              \
    const unsigned _lb = (lbase) + (bufe);                                         \
    const size_t _k0 = (size_t)((t_) << 5);                                        \
    _Pragma("unroll")                                                              \
    for (int _l = 0; _l < 2; ++_l) {                                               \
      __builtin_amdgcn_global_load_lds(                                            \
        (const __attribute__((address_space(1))) void*)((sp) + (size_t)_l * l1off + _k0), \
        (__attribute__((address_space(3))) void*)&lds[_lb + (unsigned)((_l * 512 + tid) * 8)], \
        16, 0, 0);                                                                 \
    }                                                                              \
  } while (0)

// read A half q (4 x ds_read_b128): m-tiles q*4+mi, rows wm*128 + .. + l15
#define READ_A(dst, q, bo)                                                         \
  _Pragma("unroll")                                                                \
  for (int mi = 0; mi < 4; ++mi)                                                   \
    dst[mi] = *(const bf16x8*)&lds[(bo) + Ab + (unsigned)((q) * 2048 + mi * 512)];

// read B n-half h (2 x ds_read_b128): n-tiles h*2+ni, rows wn*64 + .. + l15
#define READ_B(dst, h, bo)                                                         \
  _Pragma("unroll")                                                                \
  for (int ni = 0; ni < 2; ++ni)                                                   \
    dst[ni] = *(const bf16x8*)&lds[(bo) + Bb + (unsigned)((h) * 1024 + ni * 512)];

// one C-quadrant (q = M-half, h = N-half) x K=32: 4mi x 2ni = 8 MFMA
#define QUAD(aF, bF, q, h)                                                         \
  _Pragma("unroll")                                                                \
  for (int mi = 0; mi < 4; ++mi) {                                                 \
    _Pragma("unroll")                                                              \
    for (int ni = 0; ni < 2; ++ni) {                                               \
      acc[(q)*4+mi][(h)*2+ni] = __builtin_amdgcn_mfma_f32_16x16x32_bf16(           \
          aF[mi], bF[ni], acc[(q)*4+mi][(h)*2+ni], 0, 0, 0);                       \
    }                                                                              \
  }

// one K-tile, 2 phases: T = runtime tile index; BUFO/NBUFO = LITERAL offsets
#define KTILE2(T, BUFO, NBUFO) {                                                   \
    /* P0: read a0,b1; stage A(t+1); Q(a0,b0)+Q(a0,b1); drain; BAR */              \
    READ_A(a0, 0, BUFO);                                                           \
    READ_B(b1, 1, BUFO);                                                           \
    if ((T) < Kt - 1) STG(sA, 0u, NBUFO, (T) + 1);                                 \
    __builtin_amdgcn_s_setprio(1);                                                 \
    QUAD(a0, b0, 0, 0); QUAD(a0, b1, 0, 1);                                        \
    __builtin_amdgcn_s_setprio(0);                                                 \
    LGKM0();                                                                       \
    BAR();                                                                         \
    /* P1: read a1; stage B(t+2); Q(a1,b1)+Q(a1,b0); VMCNT; drain; BAR; b0 */      \
    READ_A(a1, 1, BUFO);                                                           \
    if ((T) < Kt - 2) STG(sB, 16384u, BUFO, (T) + 2);                              \
    __builtin_amdgcn_s_setprio(1);                                                 \
    QUAD(a1, b1, 1, 1); QUAD(a1, b0, 1, 0);                                        \
    __builtin_amdgcn_s_setprio(0);                                                 \
    if ((T) < Kt - 2)       { VMCNT(2); }                                          \
    else if ((T) == Kt - 2) { VMCNT(0); }                                          \
    LGKM0();                                                                       \
    BAR();                                                                         \
    if ((T) < Kt - 1) READ_B(b0, 0, NBUFO);                                        \
  }

__global__ __launch_bounds__(512, 4)
void gemm2p32_bt(const unsigned short* __restrict__ Ag,
                 const unsigned short* __restrict__ Bg,
                 const float* __restrict__ bias, float* __restrict__ C,
                 int M, int N, int K)
{
  __shared__ __attribute__((aligned(128))) unsigned short lds[32768];   // 64 KiB
  const int tid  = threadIdx.x;
  const int lane = tid & 63;
  const int widx = tid >> 6;              // 8 waves
  const int wm   = widx >> 2;             // 0..1  (M)
  const int wn   = widx & 3;              // 0..3  (N)

  int bid = blockIdx.x;
  const int nwg = gridDim.x;
  if ((nwg & 7) == 0) { const int cpx = nwg >> 3; bid = (bid & 7) * cpx + (bid >> 3); }
  const int nTN = N >> 8;
  const int tm = bid / nTN, tn = bid - tm * nTN;
  const int row0 = tm << 8, col0 = tn << 8;

  const int l15 = lane & 15, l16 = lane >> 4;           // l16 in 0..3 = k-slot
  // read-side swizzled k-offset (elems): slot' = l16 ^ ((l15>>1)&3)
  const unsigned koffq = (unsigned)((l16 ^ ((l15 >> 1) & 3)) * 8);
  // per-wave fragment base addresses (elems), swizzle folded in
  const unsigned Ab = (unsigned)((wm * 128 + l15) * 32) + koffq;
  const unsigned Bb = 16384u + (unsigned)((wn * 64 + l15) * 32) + koffq;

  const int Kt = K >> 5;

  // hoisted staging addressing: per-thread source base (inverse swizzle applied)
  const int sr2 = tid >> 2;                                   // row 0..127
  const int ss  = tid & 3;                                    // 16B slot
  const unsigned sks2 = (unsigned)((ss ^ ((sr2 >> 1) & 3)) * 8); // swz k-off (elems)
  const size_t l1off = (size_t)128 * K;   // _l=1 -> +128 rows
  const unsigned short* sA = Ag + (size_t)(row0 + sr2) * K + sks2;
  const unsigned short* sB = Bg + (size_t)(col0 + sr2) * K + sks2;

  f32x4 acc[8][4] = {};
  bf16x8 a0[4], a1[4], b0[2], b1[2];

  // ---- prologue: A(0),B(0) -> buf0; B(1) -> buf1; complete tile0; pre-read b0(0)
  STG(sA, 0u,     0u, 0);
  STG(sB, 16384u, 0u, 0);
  if (Kt > 1) {
    STG(sB, 16384u, 8192u, 1);
    VMCNT(2);                 // completes A(0),B(0) (4 oldest); B(1)'s 2 in flight
  } else {
    VMCNT(0);
  }
  BAR();                      // ALL waves drained tile0 -> reads below safe
  READ_B(b0, 0, 0u);          // pre-read tile0's b0 (2 reads)

  // ---- main loop: 2 K-tiles per iteration, literal buffer offsets ----
  for (int t = 0; t < Kt; t += 2) {
    KTILE2(t,     0u,    8192u);
    KTILE2(t + 1, 8192u, 0u);
  }

  // ---- epilogue: C/D layout col=lane&15, row=(lane>>4)*4+j
  #pragma unroll
  for (int n = 0; n < 4; ++n) {
    const int col = col0 + wn * 64 + n * 16 + l15;
    const float bv = bias[col];
    #pragma unroll
    for (int mi8 = 0; mi8 < 8; ++mi8) {
      #pragma unroll
      for (int j = 0; j < 4; ++j) {
        const int row = row0 + wm * 128 + mi8 * 16 + l16 * 4 + j;
        C[(size_t)row * N + col] = acc[mi8][n][j] + bv;
      }
    }
  }
}

// ---------------- fallback: 128x128 2-phase kernel (round-1, verified) ----------------
template<bool BF16SRC>
__global__ __launch_bounds__(256)
void gemm_bt_kernel(const void* __restrict__ Ap, const void* __restrict__ Bp,
                    const float* __restrict__ bias, float* __restrict__ C,
                    int M, int N, int K)
{
  constexpr int BM = 128, BN = 128, BK = 64;
  __shared__ unsigned short As[BM * BK];
  __shared__ unsigned short Bs[BN * BK];

  const int nTN = N / BN;
  int bid = blockIdx.x;
  const int nwg = gridDim.x;
  if ((nwg & 7) == 0) { const int cpx = nwg >> 3; bid = (bid & 7) * cpx + (bid >> 3); }
  const int tm = bid / nTN, tn = bid % nTN;
  const int row0 = tm * BM, col0 = tn * BN;

  const int tid  = threadIdx.x;
  const int lane = tid & 63;
  const int wid  = tid >> 6;
  const int wm   = wid >> 1;
  const int wn   = wid & 1;

  f32x4 acc[4][4] = {};

  const unsigned short* A16 = (const unsigned short*)Ap;
  const unsigned short* B16 = (const unsigned short*)Bp;
  const float* A32 = (const float*)Ap;
  const float* B32 = (const float*)Bp;

  for (int k0 = 0; k0 < K; k0 += BK) {
    if constexpr (BF16SRC) {
      #pragma unroll
      for (int j = 0; j < 4; ++j) {
        const int c  = wid * 4 + j;
        const int r  = c * 8 + (lane >> 3);
        const int kk = (lane & 7) * 8;
        __builtin_amdgcn_global_load_lds(
            (const __attribute__((address_space(1))) void*)(A16 + (size_t)(row0 + r) * K + k0 + kk),
            (__attribute__((address_space(3))) void*)(&As[c * 512]), 16, 0, 0);
      }
      #pragma unroll
      for (int j = 0; j < 4; ++j) {
        const int c  = wid * 4 + j;
        const int r  = c * 8 + (lane >> 3);
        const int kk = (lane & 7) * 8;
        __builtin_amdgcn_global_load_lds(
            (const __attribute__((address_space(1))) void*)(B16 + (size_t)(col0 + r) * K + k0 + kk),
            (__attribute__((address_space(3))) void*)(&Bs[c * 512]), 16, 0, 0);
      }
    } else {
      #pragma unroll
      for (int j = 0; j < 4; ++j) {
        const int e = (j * 256 + tid) * 8;
        const int r = e >> 6, kk = e & 63;
        floatv4 v0 = *(const floatv4*)&A32[(size_t)(row0 + r) * K + k0 + kk];
        floatv4 v1 = *(const floatv4*)&A32[(size_t)(row0 + r) * K + k0 + kk + 4];
        ushortx8 o;
        o[0] = f2bf(v0[0]); o[1] = f2bf(v0[1]); o[2] = f2bf(v0[2]); o[3] = f2bf(v0[3]);
        o[4] = f2bf(v1[0]); o[5] = f2bf(v1[1]); o[6] = f2bf(v1[2]); o[7] = f2bf(v1[3]);
        *(ushortx8*)&As[e] = o;
      }
      #pragma unroll
      for (int j = 0; j < 4; ++j) {
        const int e = (j * 256 + tid) * 8;
        const int r = e >> 6, kk = e & 63;
        floatv4 v0 = *(const floatv4*)&B32[(size_t)(col0 + r) * K + k0 + kk];
        floatv4 v1 = *(const floatv4*)&B32[(size_t)(col0 + r) * K + k0 + kk + 4];
        ushortx8 o;
        o[0] = f2bf(v0[0]); o[1] = f2bf(v0[1]); o[2] = f2bf(v0[2]); o[3] = f2bf(v0[3]);
        o[4] = f2bf(v1[0]); o[5] = f2bf(v1[1]); o[6] = f2bf(v1[2]); o[7] = f2bf(v1[3]);
        *(ushortx8*)&Bs[e] = o;
      }
    }
    __syncthreads();

    #pragma unroll
    for (int kk = 0; kk < BK / 32; ++kk) {
      const int ko = kk * 32 + (lane >> 4) * 8;
      bf16x8 a[4], b[4];
      #pragma unroll
      for (int mi = 0; mi < 4; ++mi)
        a[mi] = *(const bf16x8*)&As[(wm * 64 + mi * 16 + (lane & 15)) * BK + ko];
      #pragma unroll
      for (int ni = 0; ni < 4; ++ni)
        b[ni] = *(const bf16x8*)&Bs[(wn * 64 + ni * 16 + (lane & 15)) * BK + ko];
      #pragma unroll
      for (int mi = 0; mi < 4; ++mi)
        #pragma unroll
        for (int ni = 0; ni < 4; ++ni)
          acc[mi][ni] = __builtin_amdgcn_mfma_f32_16x16x32_bf16(a[mi], b[ni], acc[mi][ni], 0, 0, 0);
    }
    __syncthreads();
  }

  #pragma unroll
  for (int mi = 0; mi < 4; ++mi) {
    #pragma unroll
    for (int ni = 0; ni < 4; ++ni) {
      const int col = col0 + wn * 64 + ni * 16 + (lane & 15);
      const float bv = bias[col];
      #pragma unroll
      for (int j = 0; j < 4; ++j) {
        const int row = row0 + wm * 64 + mi * 16 + (lane >> 4) * 4 + j;
        C[(size_t)row * N + col] = acc[mi][ni][j] + bv;
      }
    }
  }
}

extern "C" void kernel_launch(void* const* d_in, const int* in_sizes, int n_in,
                              void* d_out, int out_size, void* d_ws, size_t ws_size,
                              hipStream_t stream) {
  const float* x = (const float*)d_in[0];
  const float* w = (const float*)d_in[1];
  const float* b = (const float*)d_in[2];
  float* out = (float*)d_out;

  const int N = in_sizes[2];            // 4096
  const int K = in_sizes[1] / N;        // 4096
  const int M = in_sizes[0] / K;        // 8192

  const size_t needed = ((size_t)M * K + (size_t)N * K) * sizeof(unsigned short);

  if (ws_size >= needed) {
    unsigned short* Abf = (unsigned short*)d_ws;
    unsigned short* Bbf = Abf + (size_t)M * K;
    const size_t nx8 = (size_t)M * K / 8;
    const size_t nt8 = nx8 + (size_t)N * K / 8;
    cvt_dual<<<2048, 256, 0, stream>>>(x, w, Abf, nx8, nt8);
    const int Kt32 = K >> 5;
    if ((M % 256) == 0 && (N % 256) == 0 && (K % 32) == 0 && K >= 192 && (Kt32 % 2) == 0) {
      const int grid = (M / 256) * (N / 256);
      gemm2p32_bt<<<grid, 512, 0, stream>>>(Abf, Bbf, b, out, M, N, K);
    } else {
      const int grid = (M / 128) * (N / 128);
      gemm_bt_kernel<true><<<grid, 256, 0, stream>>>(Abf, Bbf, b, out, M, N, K);
    }
  } else {
    const int grid = (M / 128) * (N / 128);
    gemm_bt_kernel<false><<<grid, 256, 0, stream>>>(x, w, b, out, M, N, K);
  }
}

// Round 20
// 286.904 us; speedup vs baseline: 7.5040x; 7.5040x over previous
//
#include <hip/hip_runtime.h>
#include <hip/hip_bf16.h>
#include <stdint.h>

typedef __attribute__((ext_vector_type(8))) short bf16x8;
typedef __attribute__((ext_vector_type(4))) float f32x4;
typedef __attribute__((ext_vector_type(4))) float floatv4;
typedef __attribute__((ext_vector_type(8))) unsigned short ushortx8;

// fp32 -> bf16 round-to-nearest-even (finite inputs)
__device__ __forceinline__ unsigned short f2bf(float f) {
  union { float f; uint32_t u; } c; c.f = f;
  uint32_t u = c.u;
  uint32_t r = (u + 0x7FFFu + ((u >> 16) & 1u)) >> 16;
  return (unsigned short)r;
}

// single kernel converts BOTH tensors (dst is contiguous: [x_bf16 | w_bf16])
__global__ void cvt_dual(const float* __restrict__ x, const float* __restrict__ w,
                         unsigned short* __restrict__ dst, size_t nx8, size_t nt8) {
  size_t i = (size_t)blockIdx.x * blockDim.x + threadIdx.x;
  size_t stride = (size_t)gridDim.x * blockDim.x;
  for (size_t j = i; j < nt8; j += stride) {
    const float* src = (j < nx8) ? x : w - nx8 * 8;   // src[j*8] indexes the right tensor
    floatv4 v0 = ((const floatv4*)src)[j * 2];
    floatv4 v1 = ((const floatv4*)src)[j * 2 + 1];
    ushortx8 o;
    o[0] = f2bf(v0[0]); o[1] = f2bf(v0[1]); o[2] = f2bf(v0[2]); o[3] = f2bf(v0[3]);
    o[4] = f2bf(v1[0]); o[5] = f2bf(v1[1]); o[6] = f2bf(v1[2]); o[7] = f2bf(v1[3]);
    ((ushortx8*)dst)[j] = o;
  }
}

// ------ 2-barrier-per-K-tile 256x256 bf16 GEMM (C = A*B^T + bias) ------
// 512 threads = 8 waves (2M x 4N), per-wave output 128x64, 16x16x32 MFMA.
// LDS 128 KiB: A[2buf][2half][128][64] + B[2buf][2half][128][64], bf16,
// read-side XOR swizzle k ^= (row&7)*8 (inverse pre-applied to global source).
//
// 2-phase schedule (A staged 1 tile ahead, B staged 2 tiles ahead):
//  P0(t): read a0(8)+b1(4) <-BUF; stage A_s0+A_s1(t+1)->NBUF;
//         Q(a0,b0)+Q(a0,b1); lgkmcnt(0); BAR
//  P1(t): read a1(8) <-BUF; stage B_s0+B_s1(t+2)->BUF;
//         Q(a1,b1)+Q(a1,b0); VMCNT(4); lgkmcnt(0); BAR; pre-read b0(t+1)<-NBUF
// vmcnt ledger (each STG = 2 loads; A-tile = B-tile = 4 loads):
//  entering P0(t): 4 outstanding {B(t+1)}; +4 (A(t+1)) = 8; +4 (B(t+2)) = 12;
//  VMCNT(4) completes the 8 oldest = B(t+1)+A(t+1) -> next tile fully staged
//  before BAR (all waves) -> pre-read b0(t+1) and P0(t+1) reads are safe.
//  Prologue: stage A(0),B(0),B(1) = 12 loads; VMCNT(4) completes A(0),B(0).
//  Tails: t==Kt-2 -> VMCNT(0); t==Kt-1 -> no stage/VMCNT/pre-read.
// WAR (stage >= 1 closing-barrier after the region's reads RETIRED):
//  the lgkmcnt(0) before EVERY closing BAR forces each wave's ds_reads to
//  retire before it passes the barrier (closes the r14 hazard: inline-asm
//  barriers don't order register-only MFMAs, so consumption alone is not a
//  retirement proof). Distances: A(t+1)@P0(t) after a0/a1(t-1) retired
//  P0/P1'(t-1) >=1 BAR; B(t+2)@P1'(t) after b1(t) retired P0(t)-end and
//  b0(t) (pre-read P1'(t-1), consumed P0(t)) retired P0(t)-end >=1 BAR.
// Requires Kt even (launcher guards; else fallback kernel).
// Session notes (measured): r19 BK=32 @ 4 waves/EU -> acc spills to scratch
// (10.8 GB/dispatch HBM) — this tile REQUIRES 2 waves/EU. r14: stages moved
// earlier than this ledger race (MFMA sinks past inline-asm BAR). r12: 32x32
// MFMA adds bank conflicts. r9/r10: cross-phase reg pipeline / smaller tiles
// lose to register wall / HBM reuse.

#define BAR()     do { asm volatile("" ::: "memory"); __builtin_amdgcn_s_barrier(); asm volatile("" ::: "memory"); } while (0)
#define VMCNT(n)  asm volatile("s_waitcnt vmcnt(" #n ")" ::: "memory")
#define LGKM0()   asm volatile("s_waitcnt lgkmcnt(0)" ::: "memory")

// stage one 128x64 half-tile (16 KiB) via 2x global_load_lds(16B)/thread.
// bufe = LITERAL buffer element-offset (0 / 16384); t_ only feeds the global k.
#define STG(sp, lbase, bufe, h, t_) do {                                           \
    const unsigned _lb = (lbase) + (bufe) + (unsigned)((h) * 8192);                \
    const size_t _k0 = (size_t)((t_) << 6);                                        \
    _Pragma("unroll")                                                              \
    for (int _l = 0; _l < 2; ++_l) {                                               \
      __builtin_amdgcn_global_load_lds(                                            \
        (const __attribute__((address_space(1))) void*)((sp) + (size_t)(h) * hoff + (size_t)_l * l1off + _k0), \
        (__attribute__((address_space(3))) void*)&lds[_lb + (unsigned)((_l * 512 + widx * 64) * 8)], \
        16, 0, 0);                                                                 \
    }                                                                              \
  } while (0)

// read A quad q (8 x ds_read_b128): rows q*64 + mi*16 + l15 of wave's A-half
#define READ_A(dst, q, bo)                                                         \
  _Pragma("unroll")                                                                \
  for (int mi = 0; mi < 4; ++mi) {                                                 \
    const unsigned rb = Abase + (bo) + (unsigned)((((q) * 64) + mi * 16 + l15) * 64); \
    dst[mi * 2 + 0] = *(const bf16x8*)&lds[rb + koff0];                            \
    dst[mi * 2 + 1] = *(const bf16x8*)&lds[rb + koff1];                            \
  }

// read B n-half h (4 x ds_read_b128): rows brow + h*32 + ni*16 + l15 of wave's B-half
#define READ_B(dst, h, bo)                                                         \
  _Pragma("unroll")                                                                \
  for (int ni = 0; ni < 2; ++ni) {                                                 \
    const unsigned rb = Bbase + (bo) + (brow + (unsigned)((h) * 32 + ni * 16 + l15)) * 64u; \
    dst[ni * 2 + 0] = *(const bf16x8*)&lds[rb + koff0];                            \
    dst[ni * 2 + 1] = *(const bf16x8*)&lds[rb + koff1];                            \
  }

// one C-quadrant (q = M-quad, h = N-half) x K=64: 4mi x 2ni x 2kk = 16 MFMA
#define QUAD(aF, bF, q, h)                                                         \
  _Pragma("unroll")                                                                \
  for (int mi = 0; mi < 4; ++mi) {                                                 \
    _Pragma("unroll")                                                              \
    for (int ni = 0; ni < 2; ++ni) {                                               \
      acc[(q)*4+mi][(h)*2+ni] = __builtin_amdgcn_mfma_f32_16x16x32_bf16(           \
          aF[mi*2+0], bF[ni*2+0], acc[(q)*4+mi][(h)*2+ni], 0, 0, 0);               \
      acc[(q)*4+mi][(h)*2+ni] = __builtin_amdgcn_mfma_f32_16x16x32_bf16(           \
          aF[mi*2+1], bF[ni*2+1], acc[(q)*4+mi][(h)*2+ni], 0, 0, 0);               \
    }                                                                              \
  }

// one K-tile, 2 phases: T = runtime tile index; BUFO/NBUFO = LITERAL offsets
#define KTILE2(T, BUFO, NBUFO) {                                                   \
    /* P0: read a0,b1; stage A(t+1); Q(a0,b0)+Q(a0,b1); drain; BAR */              \
    READ_A(a0, 0, BUFO);                                                           \
    READ_B(b1, 1, BUFO);                                                           \
    if ((T) < Kt - 1) { STG(sA, 0u, NBUFO, 0, (T) + 1);                            \
                        STG(sA, 0u, NBUFO, 1, (T) + 1); }                          \
    __builtin_amdgcn_s_setprio(1);                                                 \
    QUAD(a0, b0, 0, 0); QUAD(a0, b1, 0, 1);                                        \
    __builtin_amdgcn_s_setprio(0);                                                 \
    LGKM0();                                                                       \
    BAR();                                                                         \
    /* P1: read a1; stage B(t+2); Q(a1,b1)+Q(a1,b0); VMCNT; drain; BAR; b0 */      \
    READ_A(a1, 1, BUFO);                                                           \
    if ((T) < Kt - 2) { STG(sB, 32768u, BUFO, 0, (T) + 2);                         \
                        STG(sB, 32768u, BUFO, 1, (T) + 2); }                       \
    __builtin_amdgcn_s_setprio(1);                                                 \
    QUAD(a1, b1, 1, 1); QUAD(a1, b0, 1, 0);                                        \
    __builtin_amdgcn_s_setprio(0);                                                 \
    if ((T) < Kt - 2)       { VMCNT(4); }                                          \
    else if ((T) == Kt - 2) { VMCNT(0); }                                          \
    LGKM0();                                                                       \
    BAR();                                                                         \
    if ((T) < Kt - 1) READ_B(b0, 0, NBUFO);                                        \
  }

__global__ __launch_bounds__(512, 2)
void gemm2p_bt(const unsigned short* __restrict__ Ag,
               const unsigned short* __restrict__ Bg,
               const float* __restrict__ bias, float* __restrict__ C,
               int M, int N, int K)
{
  __shared__ __attribute__((aligned(128))) unsigned short lds[65536];   // 128 KiB
  const int tid  = threadIdx.x;
  const int lane = tid & 63;
  const int widx = tid >> 6;              // 8 waves
  const int wm   = widx >> 2;             // 0..1  (M)
  const int wn   = widx & 3;              // 0..3  (N)

  int bid = blockIdx.x;
  const int nwg = gridDim.x;
  if ((nwg & 7) == 0) { const int cpx = nwg >> 3; bid = (bid & 7) * cpx + (bid >> 3); }
  const int nTN = N >> 8;
  const int tm = bid / nTN, tn = bid - tm * nTN;
  const int row0 = tm << 8, col0 = tn << 8;

  const int l15 = lane & 15, l16 = lane >> 4;
  const unsigned m7    = (unsigned)((lane & 7) * 8);      // per-lane XOR mask (elems)
  const unsigned koff0 = ((unsigned)(l16 * 8)) ^ m7;      // kk=0 swizzled k-offset
  const unsigned koff1 = ((unsigned)(32 + l16 * 8)) ^ m7; // kk=1

  const int Kt = K >> 6;

  const unsigned Abase = (unsigned)(wm * 8192);               // + buf literal
  const unsigned Bbase = 32768u + (unsigned)((wn >> 1) * 8192);
  const unsigned brow  = (unsigned)((wn & 1) * 64);

  // hoisted staging addressing: per-thread source bases (swizzle pre-applied)
  const int sr = tid >> 3;                                           // 0..63
  const unsigned sks = (unsigned)(((tid & 7) * 8) ^ ((sr & 7) * 8)); // swz k-off
  const size_t l1off = (size_t)64 * K;    // _l=1 -> +64 rows
  const size_t hoff  = (size_t)128 * K;   // half 1 -> +128 rows
  const unsigned short* sA = Ag + (size_t)(row0 + sr) * K + sks;
  const unsigned short* sB = Bg + (size_t)(col0 + sr) * K + sks;

  f32x4 acc[8][4] = {};
  bf16x8 a0[8], a1[8], b0[4], b1[4];

  // ---- prologue: A(0),B(0) -> buf0; B(1) -> buf1; complete tile0; pre-read b0(0)
  STG(sA, 0u,     0u,     0, 0);
  STG(sA, 0u,     0u,     1, 0);
  STG(sB, 32768u, 0u,     0, 0);
  STG(sB, 32768u, 0u,     1, 0);
  if (Kt > 1) {
    STG(sB, 32768u, 16384u, 0, 1);
    STG(sB, 32768u, 16384u, 1, 1);
    VMCNT(4);                 // completes A(0),B(0) (8 oldest); B(1)'s 4 in flight
  } else {
    VMCNT(0);
  }
  BAR();                      // ALL waves drained tile0 -> reads below safe
  READ_B(b0, 0, 0u);          // pre-read tile0's b0 (4 reads)

  // ---- main loop: 2 K-tiles per iteration, literal buffer offsets ----
  for (int t = 0; t < Kt; t += 2) {
    KTILE2(t,     0u,     16384u);
    KTILE2(t + 1, 16384u, 0u);
  }

  // ---- epilogue: C/D layout col=lane&15, row=(lane>>4)*4+j
  #pragma unroll
  for (int n = 0; n < 4; ++n) {
    const int col = col0 + wn * 64 + n * 16 + l15;
    const float bv = bias[col];
    #pragma unroll
    for (int mi8 = 0; mi8 < 8; ++mi8) {
      #pragma unroll
      for (int j = 0; j < 4; ++j) {
        const int row = row0 + wm * 128 + mi8 * 16 + l16 * 4 + j;
        C[(size_t)row * N + col] = acc[mi8][n][j] + bv;
      }
    }
  }
}

// ---------------- fallback: 128x128 2-phase kernel (round-1, verified) ----------------
template<bool BF16SRC>
__global__ __launch_bounds__(256)
void gemm_bt_kernel(const void* __restrict__ Ap, const void* __restrict__ Bp,
                    const float* __restrict__ bias, float* __restrict__ C,
                    int M, int N, int K)
{
  constexpr int BM = 128, BN = 128, BK = 64;
  __shared__ unsigned short As[BM * BK];
  __shared__ unsigned short Bs[BN * BK];

  const int nTN = N / BN;
  int bid = blockIdx.x;
  const int nwg = gridDim.x;
  if ((nwg & 7) == 0) { const int cpx = nwg >> 3; bid = (bid & 7) * cpx + (bid >> 3); }
  const int tm = bid / nTN, tn = bid % nTN;
  const int row0 = tm * BM, col0 = tn * BN;

  const int tid  = threadIdx.x;
  const int lane = tid & 63;
  const int wid  = tid >> 6;
  const int wm   = wid >> 1;
  const int wn   = wid & 1;

  f32x4 acc[4][4] = {};

  const unsigned short* A16 = (const unsigned short*)Ap;
  const unsigned short* B16 = (const unsigned short*)Bp;
  const float* A32 = (const float*)Ap;
  const float* B32 = (const float*)Bp;

  for (int k0 = 0; k0 < K; k0 += BK) {
    if constexpr (BF16SRC) {
      #pragma unroll
      for (int j = 0; j < 4; ++j) {
        const int c  = wid * 4 + j;
        const int r  = c * 8 + (lane >> 3);
        const int kk = (lane & 7) * 8;
        __builtin_amdgcn_global_load_lds(
            (const __attribute__((address_space(1))) void*)(A16 + (size_t)(row0 + r) * K + k0 + kk),
            (__attribute__((address_space(3))) void*)(&As[c * 512]), 16, 0, 0);
      }
      #pragma unroll
      for (int j = 0; j < 4; ++j) {
        const int c  = wid * 4 + j;
        const int r  = c * 8 + (lane >> 3);
        const int kk = (lane & 7) * 8;
        __builtin_amdgcn_global_load_lds(
            (const __attribute__((address_space(1))) void*)(B16 + (size_t)(col0 + r) * K + k0 + kk),
            (__attribute__((address_space(3))) void*)(&Bs[c * 512]), 16, 0, 0);
      }
    } else {
      #pragma unroll
      for (int j = 0; j < 4; ++j) {
        const int e = (j * 256 + tid) * 8;
        const int r = e >> 6, kk = e & 63;
        floatv4 v0 = *(const floatv4*)&A32[(size_t)(row0 + r) * K + k0 + kk];
        floatv4 v1 = *(const floatv4*)&A32[(size_t)(row0 + r) * K + k0 + kk + 4];
        ushortx8 o;
        o[0] = f2bf(v0[0]); o[1] = f2bf(v0[1]); o[2] = f2bf(v0[2]); o[3] = f2bf(v0[3]);
        o[4] = f2bf(v1[0]); o[5] = f2bf(v1[1]); o[6] = f2bf(v1[2]); o[7] = f2bf(v1[3]);
        *(ushortx8*)&As[e] = o;
      }
      #pragma unroll
      for (int j = 0; j < 4; ++j) {
        const int e = (j * 256 + tid) * 8;
        const int r = e >> 6, kk = e & 63;
        floatv4 v0 = *(const floatv4*)&B32[(size_t)(col0 + r) * K + k0 + kk];
        floatv4 v1 = *(const floatv4*)&B32[(size_t)(col0 + r) * K + k0 + kk + 4];
        ushortx8 o;
        o[0] = f2bf(v0[0]); o[1] = f2bf(v0[1]); o[2] = f2bf(v0[2]); o[3] = f2bf(v0[3]);
        o[4] = f2bf(v1[0]); o[5] = f2bf(v1[1]); o[6] = f2bf(v1[2]); o[7] = f2bf(v1[3]);
        *(ushortx8*)&Bs[e] = o;
      }
    }
    __syncthreads();

    #pragma unroll
    for (int kk = 0; kk < BK / 32; ++kk) {
      const int ko = kk * 32 + (lane >> 4) * 8;
      bf16x8 a[4], b[4];
      #pragma unroll
      for (int mi = 0; mi < 4; ++mi)
        a[mi] = *(const bf16x8*)&As[(wm * 64 + mi * 16 + (lane & 15)) * BK + ko];
      #pragma unroll
      for (int ni = 0; ni < 4; ++ni)
        b[ni] = *(const bf16x8*)&Bs[(wn * 64 + ni * 16 + (lane & 15)) * BK + ko];
      #pragma unroll
      for (int mi = 0; mi < 4; ++mi)
        #pragma unroll
        for (int ni = 0; ni < 4; ++ni)
          acc[mi][ni] = __builtin_amdgcn_mfma_f32_16x16x32_bf16(a[mi], b[ni], acc[mi][ni], 0, 0, 0);
    }
    __syncthreads();
  }

  #pragma unroll
  for (int mi = 0; mi < 4; ++mi) {
    #pragma unroll
    for (int ni = 0; ni < 4; ++ni) {
      const int col = col0 + wn * 64 + ni * 16 + (lane & 15);
      const float bv = bias[col];
      #pragma unroll
      for (int j = 0; j < 4; ++j) {
        const int row = row0 + wm * 64 + mi * 16 + (lane >> 4) * 4 + j;
        C[(size_t)row * N + col] = acc[mi][ni][j] + bv;
      }
    }
  }
}

extern "C" void kernel_launch(void* const* d_in, const int* in_sizes, int n_in,
                              void* d_out, int out_size, void* d_ws, size_t ws_size,
                              hipStream_t stream) {
  const float* x = (const float*)d_in[0];
  const float* w = (const float*)d_in[1];
  const float* b = (const float*)d_in[2];
  float* out = (float*)d_out;

  const int N = in_sizes[2];            // 4096
  const int K = in_sizes[1] / N;        // 4096
  const int M = in_sizes[0] / K;        // 8192

  const size_t needed = ((size_t)M * K + (size_t)N * K) * sizeof(unsigned short);

  if (ws_size >= needed) {
    unsigned short* Abf = (unsigned short*)d_ws;
    unsigned short* Bbf = Abf + (size_t)M * K;
    const size_t nx8 = (size_t)M * K / 8;
    const size_t nt8 = nx8 + (size_t)N * K / 8;
    cvt_dual<<<2048, 256, 0, stream>>>(x, w, Abf, nx8, nt8);
    const int Kt = K >> 6;
    if ((M % 256) == 0 && (N % 256) == 0 && (K % 64) == 0 && K >= 192 && (Kt % 2) == 0) {
      const int grid = (M / 256) * (N / 256);
      gemm2p_bt<<<grid, 512, 0, stream>>>(Abf, Bbf, b, out, M, N, K);
    } else {
      const int grid = (M / 128) * (N / 128);
      gemm_bt_kernel<true><<<grid, 256, 0, stream>>>(Abf, Bbf, b, out, M, N, K);
    }
  } else {
    const int grid = (M / 128) * (N / 128);
    gemm_bt_kernel<false><<<grid, 256, 0, stream>>>(x, w, b, out, M, N, K);
  }
}